// Round 4
// baseline (1003.006 us; speedup 1.0000x reference)
//
#include <hip/hip_runtime.h>
#include <math.h>

#define N_NODES 100000
#define N_EDGES 6400000
#define F_IN 128
#define F_OUT 16
#define NB 391                 // ceil(100000/256) buckets of 256 target nodes
#define EPB3 16000             // edges per partition block: 400 * 16000 = 6.4M exactly

// -------- 1. global bucket histogram (LDS pre-aggregation) --------
__global__ void hist_kernel(const int* __restrict__ col, int* __restrict__ gbhist) {
    __shared__ int h[NB];
    const int tid = threadIdx.x;
    for (int i = tid; i < NB; i += 256) h[i] = 0;
    __syncthreads();
    const int stride = gridDim.x * 256;
    for (int e = blockIdx.x * 256 + tid; e < N_EDGES; e += stride)
        atomicAdd(&h[col[e] >> 8], 1);
    __syncthreads();
    for (int i = tid; i < NB; i += 256) if (h[i]) atomicAdd(&gbhist[i], h[i]);
}

// -------- 2. exclusive scan of 391 bucket counts (one block) --------
__global__ void scan_kernel(const int* __restrict__ gbhist, int* __restrict__ boffs,
                            int* __restrict__ gcursor) {
    __shared__ int lds[512];
    const int tid = threadIdx.x;
    int v = (tid < NB) ? gbhist[tid] : 0;
    lds[tid] = v; __syncthreads();
    for (int off = 1; off < 512; off <<= 1) {
        int t = (tid >= off) ? lds[tid - off] : 0; __syncthreads();
        lds[tid] += t; __syncthreads();
    }
    int excl = lds[tid] - v;
    if (tid < NB) { boffs[tid] = excl; gcursor[tid] = excl; }
    if (tid == NB) boffs[NB] = N_EDGES;
}

// -------- 3. partition edges into bucket-contiguous runs --------
// packed = (row << 8) | (col & 255): row < 2^17, local col < 2^8 -> fits 25 bits.
__global__ void part_kernel(const int* __restrict__ row, const int* __restrict__ col,
                            int* __restrict__ gcursor, unsigned int* __restrict__ packed) {
    __shared__ int hist[NB];
    __shared__ int base[NB];
    const int tid = threadIdx.x;
    const int e0 = blockIdx.x * EPB3, e1 = e0 + EPB3;
    for (int i = tid; i < NB; i += 256) hist[i] = 0;
    __syncthreads();
    for (int i = e0 + tid; i < e1; i += 256) atomicAdd(&hist[col[i] >> 8], 1);
    __syncthreads();
    for (int b = tid; b < NB; b += 256)
        base[b] = hist[b] ? atomicAdd(&gcursor[b], hist[b]) : 0;
    __syncthreads();
    for (int i = tid; i < NB; i += 256) hist[i] = 0;
    __syncthreads();
    for (int i = e0 + tid; i < e1; i += 256) {
        int c = col[i];
        int b = c >> 8;
        int p = base[b] + atomicAdd(&hist[b], 1);
        packed[p] = ((unsigned)row[i] << 8) | (unsigned)(c & 255);
    }
}

// -------- 4. per-bucket degree histogram -> dinv (no global atomics) --------
__global__ void deg_kernel(const unsigned int* __restrict__ packed,
                           const int* __restrict__ boffs, float* __restrict__ dinv) {
    __shared__ int dh[256];
    const int tid = threadIdx.x;
    dh[tid] = 0;
    __syncthreads();
    const int b = blockIdx.x;
    const int e = boffs[b + 1];
    for (int i = boffs[b] + tid; i < e; i += 256)
        atomicAdd(&dh[packed[i] & 255u], 1);
    __syncthreads();
    const int node = (b << 8) + tid;
    if (node < N_NODES) dinv[node] = rsqrtf((float)dh[tid] + 1.0f);  // +1 self loop
}

// -------- 5. g[n,f] = dinv[n] * sum_k x[n,k] * W[k,f]; also bf16 copy g16 --------
__global__ void gemm_kernel(const float* __restrict__ x, const float* __restrict__ W,
                            const float* __restrict__ dinv, float* __restrict__ g,
                            unsigned short* __restrict__ g16) {
    __shared__ float Ws[F_IN * F_OUT];        // 8 KB
    __shared__ float xs[16 * (F_IN + 1)];
    const int tid = threadIdx.x;
    const int n0 = blockIdx.x * 16;
    for (int i = tid; i < F_IN * F_OUT; i += 256) Ws[i] = W[i];
    const float* xbase = x + (size_t)n0 * F_IN;
    for (int i = tid; i < 16 * F_IN; i += 256) {
        int r = i >> 7, c = i & 127;
        xs[r * (F_IN + 1) + c] = xbase[i];
    }
    __syncthreads();
    const int node = tid >> 4, f = tid & 15;
    const float* xr = &xs[node * (F_IN + 1)];
    float acc = 0.f;
    #pragma unroll 8
    for (int k = 0; k < F_IN; k++) acc += xr[k] * Ws[k * 16 + f];
    const float val = acc * dinv[n0 + node];
    const int idx = n0 * 16 + tid;
    g[idx] = val;
    unsigned u = __float_as_uint(val);          // bf16 RNE round for the gather table
    u += 0x7FFFu + ((u >> 16) & 1u);
    g16[idx] = (unsigned short)(u >> 16);
}

// -------- 6. per-bucket scatter-reduce: bf16 gather (L2-resident 3.2 MB table),
//            LDS fp32 atomic accumulate, plain-store flush. 1 block/bucket. --------
__global__ void __launch_bounds__(1024) scatter_kernel(
        const unsigned int* __restrict__ packed, const int* __restrict__ boffs,
        const unsigned short* __restrict__ g16, float* __restrict__ acc) {
    __shared__ float sacc[256 * F_OUT];   // 16 KB
    const int tid = threadIdx.x;
    for (int i = tid; i < 256 * F_OUT; i += 1024) sacc[i] = 0.f;
    __syncthreads();
    const int b = blockIdx.x;
    const int s = boffs[b], e = boffs[b + 1];
    const int f = tid & 15;
    const int eg = tid >> 4;              // 0..63: 64 edges per step
    int i = s + eg;
    for (; i + 192 < e; i += 256) {       // 4x unroll: 4 gathers in flight per lane
        unsigned p0 = packed[i];
        unsigned p1 = packed[i + 64];
        unsigned p2 = packed[i + 128];
        unsigned p3 = packed[i + 192];
        float v0 = __uint_as_float((unsigned)g16[(p0 >> 8) * 16 + f] << 16);
        float v1 = __uint_as_float((unsigned)g16[(p1 >> 8) * 16 + f] << 16);
        float v2 = __uint_as_float((unsigned)g16[(p2 >> 8) * 16 + f] << 16);
        float v3 = __uint_as_float((unsigned)g16[(p3 >> 8) * 16 + f] << 16);
        atomicAdd(&sacc[((p0 & 255u) << 4) + f], v0);
        atomicAdd(&sacc[((p1 & 255u) << 4) + f], v1);
        atomicAdd(&sacc[((p2 & 255u) << 4) + f], v2);
        atomicAdd(&sacc[((p3 & 255u) << 4) + f], v3);
    }
    for (; i < e; i += 64) {
        unsigned p0 = packed[i];
        atomicAdd(&sacc[((p0 & 255u) << 4) + f],
                  __uint_as_float((unsigned)g16[(p0 >> 8) * 16 + f] << 16));
    }
    __syncthreads();
    const int nbase = b << 8;
    float* dst = acc + ((size_t)nbase << 4);
    for (int j = tid; j < 256 * F_OUT; j += 1024)
        if (nbase + (j >> 4) < N_NODES) dst[j] = sacc[j];
}

// -------- 7. out_n = tanh(dinv[n]*(acc[n]+g[n]) + b); mean over n --------
__global__ void finalize_kernel(const float* __restrict__ acc, const float* __restrict__ g,
                                const float* __restrict__ dinv, const float* __restrict__ b,
                                double* __restrict__ dsum) {
    __shared__ float s[4][16];
    const int tid = threadIdx.x;
    const int f = tid & 15;
    const float bf = b[f];
    float local = 0.f;
    for (int i = blockIdx.x * blockDim.x + tid; i < N_NODES * F_OUT;
         i += gridDim.x * blockDim.x) {
        const int n = i >> 4;
        local += tanhf(dinv[n] * (acc[i] + g[i]) + bf);
    }
    local += __shfl_down(local, 32);
    local += __shfl_down(local, 16);
    const int lane = tid & 63, wave = tid >> 6;
    if (lane < 16) s[wave][lane] = local;
    __syncthreads();
    if (tid < 16) {
        float v = s[0][tid] + s[1][tid] + s[2][tid] + s[3][tid];
        atomicAdd(&dsum[tid], (double)v);
    }
}

__global__ void out_kernel(const double* __restrict__ dsum, float* __restrict__ out) {
    const int f = threadIdx.x;
    if (f < 16) out[f] = (float)(dsum[f] * (1.0 / (double)N_NODES));
}

extern "C" void kernel_launch(void* const* d_in, const int* in_sizes, int n_in,
                              void* d_out, int out_size, void* d_ws, size_t ws_size,
                              hipStream_t stream) {
    const float* x  = (const float*)d_in[0];
    const int*   ei = (const int*)d_in[1];
    const float* W  = (const float*)d_in[2];
    const float* b  = (const float*)d_in[3];
    float* out = (float*)d_out;

    const int* row = ei;             // edge_index[0] = source
    const int* col = ei + N_EDGES;   // edge_index[1] = target

    // workspace layout (~42 MB):
    char* p = (char*)d_ws;
    double*         dsum    = (double*)p;          p += 16 * 8;
    int*            gbhist  = (int*)p;             p += NB * 4;
    int*            gcursor = (int*)p;             p += NB * 4;
    int*            boffs   = (int*)p;             p += (NB + 1) * 4;
    float*          dinv    = (float*)p;           p += (size_t)N_NODES * 4;
    float*          g       = (float*)p;           p += (size_t)N_NODES * F_OUT * 4;
    unsigned short* g16     = (unsigned short*)p;  p += (size_t)N_NODES * F_OUT * 2;
    unsigned int*   packed  = (unsigned int*)p;    p += (size_t)N_EDGES * 4;
    float*          acc     = (float*)p;           // 6.4 MB

    // zero dsum + gbhist (contiguous)
    hipMemsetAsync(dsum, 0, 16 * 8 + NB * 4, stream);

    hist_kernel    <<<400, 256, 0, stream>>>(col, gbhist);
    scan_kernel    <<<1, 512, 0, stream>>>(gbhist, boffs, gcursor);
    part_kernel    <<<400, 256, 0, stream>>>(row, col, gcursor, packed);
    deg_kernel     <<<NB, 256, 0, stream>>>(packed, boffs, dinv);
    gemm_kernel    <<<N_NODES / 16, 256, 0, stream>>>(x, W, dinv, g, g16);
    scatter_kernel <<<NB, 1024, 0, stream>>>(packed, boffs, g16, acc);
    finalize_kernel<<<640, 256, 0, stream>>>(acc, g, dinv, b, dsum);
    out_kernel     <<<1, 16, 0, stream>>>(dsum, out);
}

// Round 5
// 393.500 us; speedup vs baseline: 2.5489x; 2.5489x over previous
//
#include <hip/hip_runtime.h>
#include <math.h>

#define N_NODES 100000
#define N_EDGES 6400000
#define F_IN 128
#define F_OUT 16
#define NB 391                 // ceil(100000/256) buckets of 256 target nodes
#define EPB3 16000             // edges per partition block: 400 * 16000 = 6.4M exactly
#define FPSCALE 524288.0f      // 2^19 fixed-point scale for LDS int accumulation
#define FPINV   (1.0f / 524288.0f)

// -------- 1. global bucket histogram (LDS pre-aggregation) --------
__global__ void hist_kernel(const int* __restrict__ col, int* __restrict__ gbhist) {
    __shared__ int h[NB];
    const int tid = threadIdx.x;
    for (int i = tid; i < NB; i += 256) h[i] = 0;
    __syncthreads();
    const int stride = gridDim.x * 256;
    for (int e = blockIdx.x * 256 + tid; e < N_EDGES; e += stride)
        atomicAdd(&h[col[e] >> 8], 1);
    __syncthreads();
    for (int i = tid; i < NB; i += 256) if (h[i]) atomicAdd(&gbhist[i], h[i]);
}

// -------- 2. exclusive scan of 391 bucket counts (one block) --------
__global__ void scan_kernel(const int* __restrict__ gbhist, int* __restrict__ boffs,
                            int* __restrict__ gcursor) {
    __shared__ int lds[512];
    const int tid = threadIdx.x;
    int v = (tid < NB) ? gbhist[tid] : 0;
    lds[tid] = v; __syncthreads();
    for (int off = 1; off < 512; off <<= 1) {
        int t = (tid >= off) ? lds[tid - off] : 0; __syncthreads();
        lds[tid] += t; __syncthreads();
    }
    int excl = lds[tid] - v;
    if (tid < NB) { boffs[tid] = excl; gcursor[tid] = excl; }
    if (tid == NB) boffs[NB] = N_EDGES;
}

// -------- 3. partition edges into bucket-contiguous runs --------
// packed = (row << 8) | (col & 255): row < 2^17, local col < 2^8 -> fits 25 bits.
__global__ void part_kernel(const int* __restrict__ row, const int* __restrict__ col,
                            int* __restrict__ gcursor, unsigned int* __restrict__ packed) {
    __shared__ int hist[NB];
    __shared__ int base[NB];
    const int tid = threadIdx.x;
    const int e0 = blockIdx.x * EPB3, e1 = e0 + EPB3;
    for (int i = tid; i < NB; i += 256) hist[i] = 0;
    __syncthreads();
    for (int i = e0 + tid; i < e1; i += 256) atomicAdd(&hist[col[i] >> 8], 1);
    __syncthreads();
    for (int b = tid; b < NB; b += 256)
        base[b] = hist[b] ? atomicAdd(&gcursor[b], hist[b]) : 0;
    __syncthreads();
    for (int i = tid; i < NB; i += 256) hist[i] = 0;
    __syncthreads();
    for (int i = e0 + tid; i < e1; i += 256) {
        int c = col[i];
        int b = c >> 8;
        int p = base[b] + atomicAdd(&hist[b], 1);
        packed[p] = ((unsigned)row[i] << 8) | (unsigned)(c & 255);
    }
}

// -------- 4. per-bucket degree histogram -> dinv (no global atomics) --------
__global__ void deg_kernel(const unsigned int* __restrict__ packed,
                           const int* __restrict__ boffs, float* __restrict__ dinv) {
    __shared__ int dh[256];
    const int tid = threadIdx.x;
    dh[tid] = 0;
    __syncthreads();
    const int b = blockIdx.x;
    const int e = boffs[b + 1];
    for (int i = boffs[b] + tid; i < e; i += 256)
        atomicAdd(&dh[packed[i] & 255u], 1);
    __syncthreads();
    const int node = (b << 8) + tid;
    if (node < N_NODES) dinv[node] = rsqrtf((float)dh[tid] + 1.0f);  // +1 self loop
}

// -------- 5. g[n,f] = dinv[n] * sum_k x[n,k] * W[k,f]; also bf16 copy g16 --------
__global__ void gemm_kernel(const float* __restrict__ x, const float* __restrict__ W,
                            const float* __restrict__ dinv, float* __restrict__ g,
                            unsigned short* __restrict__ g16) {
    __shared__ float Ws[F_IN * F_OUT];        // 8 KB
    __shared__ float xs[16 * (F_IN + 1)];
    const int tid = threadIdx.x;
    const int n0 = blockIdx.x * 16;
    for (int i = tid; i < F_IN * F_OUT; i += 256) Ws[i] = W[i];
    const float* xbase = x + (size_t)n0 * F_IN;
    for (int i = tid; i < 16 * F_IN; i += 256) {
        int r = i >> 7, c = i & 127;
        xs[r * (F_IN + 1) + c] = xbase[i];
    }
    __syncthreads();
    const int node = tid >> 4, f = tid & 15;
    const float* xr = &xs[node * (F_IN + 1)];
    float acc = 0.f;
    #pragma unroll 8
    for (int k = 0; k < F_IN; k++) acc += xr[k] * Ws[k * 16 + f];
    const float val = acc * dinv[n0 + node];
    const int idx = n0 * 16 + tid;
    g[idx] = val;
    unsigned u = __float_as_uint(val);          // bf16 RNE round for the gather table
    u += 0x7FFFu + ((u >> 16) & 1u);
    g16[idx] = (unsigned short)(u >> 16);
}

// -------- 6. per-bucket scatter-reduce: bf16 gather (L2-resident 3.2 MB table),
//            LDS INT fixed-point atomic accumulate (native ds_add_u32, no CAS loop),
//            plain-store flush. 1 block/bucket. --------
__global__ void __launch_bounds__(1024) scatter_kernel(
        const unsigned int* __restrict__ packed, const int* __restrict__ boffs,
        const unsigned short* __restrict__ g16, float* __restrict__ acc) {
    __shared__ int sacc[256 * F_OUT];   // 16 KB
    const int tid = threadIdx.x;
    for (int i = tid; i < 256 * F_OUT; i += 1024) sacc[i] = 0;
    __syncthreads();
    const int b = blockIdx.x;
    const int s = boffs[b], e = boffs[b + 1];
    const int f = tid & 15;
    const int eg = tid >> 4;              // 0..63: 64 edges per step
    int i = s + eg;
    for (; i + 192 < e; i += 256) {       // 4x unroll: 4 gathers in flight per lane
        unsigned p0 = packed[i];
        unsigned p1 = packed[i + 64];
        unsigned p2 = packed[i + 128];
        unsigned p3 = packed[i + 192];
        float v0 = __uint_as_float((unsigned)g16[(p0 >> 8) * 16 + f] << 16);
        float v1 = __uint_as_float((unsigned)g16[(p1 >> 8) * 16 + f] << 16);
        float v2 = __uint_as_float((unsigned)g16[(p2 >> 8) * 16 + f] << 16);
        float v3 = __uint_as_float((unsigned)g16[(p3 >> 8) * 16 + f] << 16);
        atomicAdd(&sacc[((p0 & 255u) << 4) + f], __float2int_rn(v0 * FPSCALE));
        atomicAdd(&sacc[((p1 & 255u) << 4) + f], __float2int_rn(v1 * FPSCALE));
        atomicAdd(&sacc[((p2 & 255u) << 4) + f], __float2int_rn(v2 * FPSCALE));
        atomicAdd(&sacc[((p3 & 255u) << 4) + f], __float2int_rn(v3 * FPSCALE));
    }
    for (; i < e; i += 64) {
        unsigned p0 = packed[i];
        float v0 = __uint_as_float((unsigned)g16[(p0 >> 8) * 16 + f] << 16);
        atomicAdd(&sacc[((p0 & 255u) << 4) + f], __float2int_rn(v0 * FPSCALE));
    }
    __syncthreads();
    const int nbase = b << 8;
    float* dst = acc + ((size_t)nbase << 4);
    for (int j = tid; j < 256 * F_OUT; j += 1024)
        if (nbase + (j >> 4) < N_NODES) dst[j] = (float)sacc[j] * FPINV;
}

// -------- 7. out_n = tanh(dinv[n]*(acc[n]+g[n]) + b); mean over n --------
__global__ void finalize_kernel(const float* __restrict__ acc, const float* __restrict__ g,
                                const float* __restrict__ dinv, const float* __restrict__ b,
                                double* __restrict__ dsum) {
    __shared__ float s[4][16];
    const int tid = threadIdx.x;
    const int f = tid & 15;
    const float bf = b[f];
    float local = 0.f;
    for (int i = blockIdx.x * blockDim.x + tid; i < N_NODES * F_OUT;
         i += gridDim.x * blockDim.x) {
        const int n = i >> 4;
        local += tanhf(dinv[n] * (acc[i] + g[i]) + bf);
    }
    local += __shfl_down(local, 32);
    local += __shfl_down(local, 16);
    const int lane = tid & 63, wave = tid >> 6;
    if (lane < 16) s[wave][lane] = local;
    __syncthreads();
    if (tid < 16) {
        float v = s[0][tid] + s[1][tid] + s[2][tid] + s[3][tid];
        atomicAdd(&dsum[tid], (double)v);
    }
}

__global__ void out_kernel(const double* __restrict__ dsum, float* __restrict__ out) {
    const int f = threadIdx.x;
    if (f < 16) out[f] = (float)(dsum[f] * (1.0 / (double)N_NODES));
}

extern "C" void kernel_launch(void* const* d_in, const int* in_sizes, int n_in,
                              void* d_out, int out_size, void* d_ws, size_t ws_size,
                              hipStream_t stream) {
    const float* x  = (const float*)d_in[0];
    const int*   ei = (const int*)d_in[1];
    const float* W  = (const float*)d_in[2];
    const float* b  = (const float*)d_in[3];
    float* out = (float*)d_out;

    const int* row = ei;             // edge_index[0] = source
    const int* col = ei + N_EDGES;   // edge_index[1] = target

    // workspace layout (~42 MB):
    char* p = (char*)d_ws;
    double*         dsum    = (double*)p;          p += 16 * 8;
    int*            gbhist  = (int*)p;             p += NB * 4;
    int*            gcursor = (int*)p;             p += NB * 4;
    int*            boffs   = (int*)p;             p += (NB + 1) * 4;
    float*          dinv    = (float*)p;           p += (size_t)N_NODES * 4;
    float*          g       = (float*)p;           p += (size_t)N_NODES * F_OUT * 4;
    unsigned short* g16     = (unsigned short*)p;  p += (size_t)N_NODES * F_OUT * 2;
    unsigned int*   packed  = (unsigned int*)p;    p += (size_t)N_EDGES * 4;
    float*          acc     = (float*)p;           // 6.4 MB

    // zero dsum + gbhist (contiguous)
    hipMemsetAsync(dsum, 0, 16 * 8 + NB * 4, stream);

    hist_kernel    <<<400, 256, 0, stream>>>(col, gbhist);
    scan_kernel    <<<1, 512, 0, stream>>>(gbhist, boffs, gcursor);
    part_kernel    <<<400, 256, 0, stream>>>(row, col, gcursor, packed);
    deg_kernel     <<<NB, 256, 0, stream>>>(packed, boffs, dinv);
    gemm_kernel    <<<N_NODES / 16, 256, 0, stream>>>(x, W, dinv, g, g16);
    scatter_kernel <<<NB, 1024, 0, stream>>>(packed, boffs, g16, acc);
    finalize_kernel<<<640, 256, 0, stream>>>(acc, g, dinv, b, dsum);
    out_kernel     <<<1, 16, 0, stream>>>(dsum, out);
}